// Round 8
// baseline (231.018 us; speedup 1.0000x reference)
//
#include <hip/hip_runtime.h>
#include <math.h>

#define NROWS 131072
#define XC    17      // FLOW_SIZE+1
#define ROWSB 64      // rows per block
#define NTHR  128     // 2 waves per block (R21)
#define HID   256
#define NB    128
#define NCOL  1024
#define LOG2E 1.44269504088896340736f

typedef __attribute__((ext_vector_type(8))) short bf16x8;
typedef __attribute__((ext_vector_type(4))) float f32x4;

#if __has_builtin(__builtin_amdgcn_exp2f)
#define EXP2F(v) __builtin_amdgcn_exp2f(v)
#else
#define EXP2F(v) exp2f(v)
#endif
#if __has_builtin(__builtin_amdgcn_rcpf)
#define RCPF(v) __builtin_amdgcn_rcpf(v)
#else
#define RCPF(v) (1.f / (v))
#endif

__device__ __forceinline__ unsigned short f2bf(float f) {
    unsigned int u = __float_as_uint(f);
    return (unsigned short)((u + 0x7FFFu + ((u >> 16) & 1u)) >> 16);  // RNE
}

// 16-lane reduction on the VALU via DPP (validated; no LDS-pipe traffic).
__device__ __forceinline__ float red16(float v) {
    int x;
    x = __builtin_amdgcn_update_dpp(0, __float_as_int(v), 0xB1, 0xF, 0xF, true);
    v += __int_as_float(x);
    x = __builtin_amdgcn_update_dpp(0, __float_as_int(v), 0x4E, 0xF, 0xF, true);
    v += __int_as_float(x);
    x = __builtin_amdgcn_update_dpp(0, __float_as_int(v), 0x141, 0xF, 0xF, true);
    v += __int_as_float(x);
    x = __builtin_amdgcn_update_dpp(0, __float_as_int(v), 0x140, 0xF, 0xF, true);
    v += __int_as_float(x);
    return v;
}

// R13: coalesced LDS-transpose prep (unchanged).
__global__ void prep_w2(const float* __restrict__ W2, unsigned short* __restrict__ w2t) {
    __shared__ __align__(16) unsigned short tkT[32][80];  // [col][k], stride 160B
    const int tid = threadIdx.x;
    const int k0 = (blockIdx.x & 3) * 64;
    const int c0 = (blockIdx.x >> 2) * 32;
    const int c4 = (tid & 7) * 4;        // 4-col group
    const int kk = (tid >> 3) * 2;       // k-pair
    const float4 r0 = *(const float4*)&W2[(size_t)(k0 + kk) * NCOL + c0 + c4];
    const float4 r1 = *(const float4*)&W2[(size_t)(k0 + kk + 1) * NCOL + c0 + c4];
    const float v0[4] = {r0.x, r0.y, r0.z, r0.w};
    const float v1[4] = {r1.x, r1.y, r1.z, r1.w};
    #pragma unroll
    for (int i = 0; i < 4; ++i) {
        const unsigned int p = (unsigned int)f2bf(v0[i] * LOG2E)
                             | ((unsigned int)f2bf(v1[i] * LOG2E) << 16);
        *(unsigned int*)&tkT[c4 + i][kk] = p;
    }
    __syncthreads();
    const int g = tid & 7, c = tid >> 3;
    const uint4 q = *(const uint4*)&tkT[c][g * 8];
    *(uint4*)&w2t[(size_t)(c0 + c) * HID + k0 + ((g ^ (c & 7)) << 3)] = q;
}

// R21: the invariant ~117us is the CU LDS pipe at ~94% (B-frag ds_read_b128:
// 4 waves x 512 x 12cy + stage writes ~= 33K cyc per 64-row block, x8
// blocks/CU ~= the whole wall). rt=2 halves per-row B-read traffic (one
// B-frag feeds 2 MFMAs) -- R0 proved the halving (41% pipe) but sat at 2
// barrier domains/CU. This round: 2-WAVE blocks (128 thr, 64 rows, wave =
// 32 rows x 128 cols, rt=2) -> LDS 37120 B -> 4 blocks/CU = 4 independent
// barrier domains, per-CU LDS demand ~148K cyc (~60%). All components are
// validated patterns: R0's afr/MFMA/epilogue, R16's stage+swizzle.
__global__ __launch_bounds__(NTHR, 2)
void gplc6(const float* __restrict__ x,
           const float* __restrict__ W1,
           const float* __restrict__ b1,
           const unsigned short* __restrict__ w2t,
           const float* __restrict__ b2,
           float* __restrict__ out)
{
    __shared__ float xs[ROWSB * XC];                       // 4352 B
    __shared__ __align__(16) union {
        unsigned short hb[ROWSB * HID];                    // 32 KB (phase 1)
        unsigned short w2[2][NB * 64];                     // 32 KB (t-loop dbuf)
    } u;                                                   // total 37120 B -> 4 blocks/CU

    const int tid  = threadIdx.x;
    const int lane = tid & 63;
    const int w    = tid >> 6;        // wave 0..1 -> rows w*32..w*32+31
    const int quad = lane >> 4;
    const int l15  = lane & 15;
    const int wr   = w * 32;
    const int ksw  = (lane & 7) << 3; // B-frag k swizzle (validated: 0 conflicts)
    const size_t r0 = (size_t)blockIdx.x * ROWSB;

    for (int i = tid; i < ROWSB * XC; i += NTHR) xs[i] = x[r0 * XC + i];
    const int cp = tid;               // col-pair 0..127
    float w1r[16];
    #pragma unroll
    for (int i = 0; i < 8; ++i) {
        const float2 t2 = *(const float2*)&W1[i * HID + 2 * cp];
        w1r[2 * i] = t2.x; w1r[2 * i + 1] = t2.y;
    }
    const float2 b1v = *(const float2*)&b1[2 * cp];
    __syncthreads();

    // ---- phase 1: h = relu(xA@W1+b1) -> bf16 LDS, granule-XOR row swizzle.
    // 128 threads x 2 cols each; every thread walks all 64 rows.
    for (int row = 0; row < ROWSB; ++row) {
        float a0 = b1v.x, a1 = b1v.y;
        #pragma unroll
        for (int i = 0; i < 8; ++i) {
            const float xv = xs[row * XC + i];
            a0 = fmaf(xv, w1r[2 * i], a0);
            a1 = fmaf(xv, w1r[2 * i + 1], a1);
        }
        a0 = fmaxf(a0, 0.f); a1 = fmaxf(a1, 0.f);
        const int eidx = row * HID + (((cp >> 2) ^ (row & 15)) << 3) + ((cp & 3) << 1);
        *(unsigned int*)&u.hb[eidx] = (unsigned int)f2bf(a0) | ((unsigned int)f2bf(a1) << 16);
    }
    __syncthreads();

    // ---- A-fragment register cache: 32 rows x 256 K per wave (64 VGPR).
    bf16x8 afr[2][8];
    #pragma unroll
    for (int rt = 0; rt < 2; ++rt)
        #pragma unroll
        for (int kf = 0; kf < 8; ++kf) {
            const int row = wr + rt * 16 + l15;    // row&15 == l15
            afr[rt][kf] = *(const bf16x8*)&u.hb[row * HID + (((kf * 4 + quad) ^ l15) << 3)];
        }
    __syncthreads();   // hb dead; union region becomes w2 dbuf

    // stage chunk n (n = t*4+kc): 128 cols x 64 k = 16 KB; 16 granules,
    // 8 per wave (wave-uniform LDS base; validated granule-XOR source).
    auto stage = [&](int n) {
        const int t = n >> 2, kc = n & 3, buf = n & 1;
        #pragma unroll
        for (int j = 0; j < 8; ++j) {
            const int ob = (w * 8 + j) * 512;              // wave-uniform LDS base
            const int c  = (ob >> 6) + (lane >> 3);        // local col 0..127
            const int kl = (lane & 7) << 3;
            const unsigned short* gp = w2t + (size_t)(t * NB + c) * HID + kc * 64 + kl;
            unsigned short* lp = &u.w2[buf][ob];
            __builtin_amdgcn_global_load_lds(
                (const __attribute__((address_space(1))) unsigned int*)gp,
                (__attribute__((address_space(3))) unsigned int*)lp, 16, 0, 0);
        }
    };

    float jf[2][4] = {{1.f,1.f,1.f,1.f},{1.f,1.f,1.f,1.f}};

    stage(0);
    #pragma unroll 1
    for (int t = 0; t < 8; ++t) {
        f32x4 acc[2][8];
        #pragma unroll
        for (int rt = 0; rt < 2; ++rt)
            #pragma unroll
            for (int ct = 0; ct < 8; ++ct) acc[rt][ct] = (f32x4){0.f, 0.f, 0.f, 0.f};

        #pragma unroll
        for (int kc = 0; kc < 4; ++kc) {          // STATIC unroll -> static afr idx
            __syncthreads();                       // chunk staged; prev buf readers done
            const int n = t * 4 + kc;
            if (n < 31) stage(n + 1);
            const unsigned short* wsb = u.w2[kc & 1];
            #pragma unroll
            for (int ks = 0; ks < 2; ++ks) {
                const int kf = kc * 2 + ks;        // compile-time
                const int klog = ks * 32 + quad * 8;
                #pragma unroll
                for (int ct = 0; ct < 8; ++ct) {
                    const int c = ct * 16 + l15;
                    const bf16x8 bf = *(const bf16x8*)&wsb[c * 64 + (klog ^ ksw)];
                    acc[0][ct] = __builtin_amdgcn_mfma_f32_16x16x32_bf16(afr[0][kf], bf, acc[0][ct], 0, 0, 0);
                    acc[1][ct] = __builtin_amdgcn_mfma_f32_16x16x32_bf16(afr[1][kf], bf, acc[1][ct], 0, 0, 0);
                }
            }
        }

        // ---- fused epilogue for transform t (wave covers full 128-col row)
        float bb[8];
        #pragma unroll
        for (int ct = 0; ct < 8; ++ct) bb[ct] = b2[t * NB + ct * 16 + l15] * LOG2E;
        #pragma unroll
        for (int rt = 0; rt < 2; ++rt)
            #pragma unroll
            for (int i = 0; i < 4; ++i) {
                const int row = wr + rt * 16 + quad * 4 + i;
                const float alpha = xs[row * XC + 8 + t] * 128.f;   // broadcast
                const float fb = floorf(alpha);
                const int bin = min(max((int)fb, 0), 127);
                const float fr = alpha - fb;
                float e[8];
                #pragma unroll
                for (int ct = 0; ct < 8; ++ct) e[ct] = EXP2F(acc[rt][ct][i] + bb[ct]);
                const float P1 = e[0],      P2 = P1 + e[1], P3 = P2 + e[2], P4 = P3 + e[3];
                const float P5 = P4 + e[4], P6 = P5 + e[5], P7 = P6 + e[6], P8 = P7 + e[7];
                int thr = (bin - l15 + 15) >> 4;           // ceil((bin-l15)/16)
                thr = min(max(thr, 0), 8);
                const float sA = (thr & 1) ? P1 : 0.f;
                const float sB = (thr & 1) ? P3 : P2;
                const float sC = (thr & 1) ? P5 : P4;
                const float sD = (thr & 1) ? P7 : P6;
                const float sE = (thr & 2) ? sB : sA;
                const float sF = (thr & 2) ? sD : sC;
                float num = (thr & 4) ? sF : sE;
                num = (thr >= 8) ? P8 : num;
                const int cb = bin >> 4;
                const float t1 = (cb & 1) ? e[1] : e[0];
                const float t2 = (cb & 1) ? e[3] : e[2];
                const float t3 = (cb & 1) ? e[5] : e[4];
                const float t4 = (cb & 1) ? e[7] : e[6];
                const float u1 = (cb & 2) ? t2 : t1;
                const float u2 = (cb & 2) ? t4 : t3;
                const float es = (cb & 4) ? u2 : u1;
                float eb  = ((bin & 15) == l15) ? es : 0.f;
                float tot = P8;
                tot = red16(tot); num = red16(num); eb = red16(eb);
                const float inv = RCPF(tot);
                jf[rt][i] *= 128.f * eb * inv;
                if (l15 == 0) xs[row * XC + 8 + t] = fmaf(eb, fr, num) * inv;
            }
    }

    // jacobian into xs, then one fully-coalesced block copy-out
    if (l15 == 0) {
        #pragma unroll
        for (int rt = 0; rt < 2; ++rt)
            #pragma unroll
            for (int i = 0; i < 4; ++i) {
                const int row = wr + rt * 16 + quad * 4 + i;
                xs[row * XC + 16] *= jf[rt][i];
            }
    }
    __syncthreads();
    for (int i = tid; i < ROWSB * XC; i += NTHR) out[r0 * XC + i] = xs[i];
}

extern "C" void kernel_launch(void* const* d_in, const int* in_sizes, int n_in,
                              void* d_out, int out_size, void* d_ws, size_t ws_size,
                              hipStream_t stream) {
    (void)in_sizes; (void)n_in; (void)ws_size; (void)out_size;
    prep_w2<<<128, 256, 0, stream>>>((const float*)d_in[3], (unsigned short*)d_ws);
    gplc6<<<NROWS / ROWSB, NTHR, 0, stream>>>(
        (const float*)d_in[0], (const float*)d_in[1], (const float*)d_in[2],
        (const unsigned short*)d_ws, (const float*)d_in[4], (float*)d_out);
}

// Round 9
// 203.959 us; speedup vs baseline: 1.1327x; 1.1327x over previous
//
#include <hip/hip_runtime.h>
#include <math.h>

#define NROWS 131072
#define XC    17      // FLOW_SIZE+1
#define ROWSB 64      // rows per block
#define HID   256
#define NB    128
#define NCOL  1024
#define LOG2E 1.44269504088896340736f

typedef __attribute__((ext_vector_type(8))) short bf16x8;
typedef __attribute__((ext_vector_type(4))) float f32x4;

#if __has_builtin(__builtin_amdgcn_exp2f)
#define EXP2F(v) __builtin_amdgcn_exp2f(v)
#else
#define EXP2F(v) exp2f(v)
#endif
#if __has_builtin(__builtin_amdgcn_rcpf)
#define RCPF(v) __builtin_amdgcn_rcpf(v)
#else
#define RCPF(v) (1.f / (v))
#endif

__device__ __forceinline__ unsigned short f2bf(float f) {
    unsigned int u = __float_as_uint(f);
    return (unsigned short)((u + 0x7FFFu + ((u >> 16) & 1u)) >> 16);  // RNE
}

// 16-lane reduction on the VALU via DPP (validated; no LDS-pipe traffic).
__device__ __forceinline__ float red16(float v) {
    int x;
    x = __builtin_amdgcn_update_dpp(0, __float_as_int(v), 0xB1, 0xF, 0xF, true);
    v += __int_as_float(x);
    x = __builtin_amdgcn_update_dpp(0, __float_as_int(v), 0x4E, 0xF, 0xF, true);
    v += __int_as_float(x);
    x = __builtin_amdgcn_update_dpp(0, __float_as_int(v), 0x141, 0xF, 0xF, true);
    v += __int_as_float(x);
    x = __builtin_amdgcn_update_dpp(0, __float_as_int(v), 0x140, 0xF, 0xF, true);
    v += __int_as_float(x);
    return v;
}

// R13: coalesced LDS-transpose prep (unchanged).
__global__ void prep_w2(const float* __restrict__ W2, unsigned short* __restrict__ w2t) {
    __shared__ __align__(16) unsigned short tkT[32][80];  // [col][k], stride 160B
    const int tid = threadIdx.x;
    const int k0 = (blockIdx.x & 3) * 64;
    const int c0 = (blockIdx.x >> 2) * 32;
    const int c4 = (tid & 7) * 4;        // 4-col group
    const int kk = (tid >> 3) * 2;       // k-pair
    const float4 r0 = *(const float4*)&W2[(size_t)(k0 + kk) * NCOL + c0 + c4];
    const float4 r1 = *(const float4*)&W2[(size_t)(k0 + kk + 1) * NCOL + c0 + c4];
    const float v0[4] = {r0.x, r0.y, r0.z, r0.w};
    const float v1[4] = {r1.x, r1.y, r1.z, r1.w};
    #pragma unroll
    for (int i = 0; i < 4; ++i) {
        const unsigned int p = (unsigned int)f2bf(v0[i] * LOG2E)
                             | ((unsigned int)f2bf(v1[i] * LOG2E) << 16);
        *(unsigned int*)&tkT[c4 + i][kk] = p;
    }
    __syncthreads();
    const int g = tid & 7, c = tid >> 3;
    const uint4 q = *(const uint4*)&tkT[c][g * 8];
    *(uint4*)&w2t[(size_t)(c0 + c) * HID + k0 + ((g ^ (c & 7)) << 3)] = q;
}

// R22: clean col-split on the R16 skeleton. LDS-byte model: R16's 4 waves
// each read the full 64KB B-tile per t (2MB/block) -> ~73% LDS-pipe busy =
// the 117us invariant. Col-split (4 waves = 2 row x 2 col groups, each 32
// rows x 64 cols) halves B-read amplification. R19 proved the additive
// merge correct but was contaminated (spills, global-x re-read, serialized
// combine); this round keeps R16's phase-1/staging byte-identical, merges
// symmetrically, and uses launch_bounds(256,3) so the ~130-reg peak cannot
// spill. Guards: WRITE_SIZE must stay 8704 KB, FETCH ~6.5 MB.
__global__ __launch_bounds__(256, 3)
void gplc6(const float* __restrict__ x,
           const float* __restrict__ W1,
           const float* __restrict__ b1,
           const unsigned short* __restrict__ w2t,
           const float* __restrict__ b2,
           float* __restrict__ out)
{
    __shared__ float xs[ROWSB * XC];                       // 4352 B
    __shared__ __align__(16) union {
        unsigned short hb[ROWSB * HID];                    // 32 KB (phase 1)
        struct {
            unsigned short w2[2][NB * 64];                 // 32 KB (t-loop dbuf)
            float mrg[2][ROWSB][4];                        // 2 KB merge triples
        } g;
    } u;                                                   // 34816 B; total 39168 B

    const int tid  = threadIdx.x;
    const int lane = tid & 63;
    const int w    = tid >> 6;
    const int rw   = w & 1;           // row group: rows rw*32 .. rw*32+31
    const int cw   = w >> 1;          // col group: cols cw*64 .. cw*64+63
    const int quad = lane >> 4;
    const int l15  = lane & 15;
    const int ksw  = (lane & 7) << 3; // B-frag k swizzle (validated: 0 conflicts)
    const size_t r0 = (size_t)blockIdx.x * ROWSB;

    for (int i = tid; i < ROWSB * XC; i += 256) xs[i] = x[r0 * XC + i];
    const int cp = tid & 127, hlf = tid >> 7;
    float w1r[16];
    #pragma unroll
    for (int i = 0; i < 8; ++i) {
        const float2 t2 = *(const float2*)&W1[i * HID + 2 * cp];
        w1r[2 * i] = t2.x; w1r[2 * i + 1] = t2.y;
    }
    const float2 b1v = *(const float2*)&b1[2 * cp];
    __syncthreads();

    // ---- phase 1: EXACT R16 pattern. h = relu(xA@W1+b1) -> bf16 LDS,
    // granule-XOR row swizzle; 128 col-pair threads x 32 rows each half.
    for (int r = 0; r < 32; ++r) {
        const int row = hlf * 32 + r;
        float a0 = b1v.x, a1 = b1v.y;
        #pragma unroll
        for (int i = 0; i < 8; ++i) {
            const float xv = xs[row * XC + i];
            a0 = fmaf(xv, w1r[2 * i], a0);
            a1 = fmaf(xv, w1r[2 * i + 1], a1);
        }
        a0 = fmaxf(a0, 0.f); a1 = fmaxf(a1, 0.f);
        const int eidx = row * HID + (((cp >> 2) ^ (row & 15)) << 3) + ((cp & 3) << 1);
        *(unsigned int*)&u.hb[eidx] = (unsigned int)f2bf(a0) | ((unsigned int)f2bf(a1) << 16);
    }
    __syncthreads();

    // ---- A-fragment register cache: 32 rows x 256 K per wave (64 VGPR).
    bf16x8 afr[2][8];
    #pragma unroll
    for (int rt = 0; rt < 2; ++rt)
        #pragma unroll
        for (int kf = 0; kf < 8; ++kf) {
            const int row = rw * 32 + rt * 16 + l15;    // row&15 == l15
            afr[rt][kf] = *(const bf16x8*)&u.hb[row * HID + (((kf * 4 + quad) ^ l15) << 3)];
        }
    __syncthreads();   // hb dead; union region becomes w2 dbuf + mrg

    // stage chunk n (n = t*4+kc): EXACT R16 pattern (128 cols x 64 k, 16KB).
    auto stage = [&](int n) {
        const int t = n >> 2, kc = n & 3, buf = n & 1;
        #pragma unroll
        for (int j = 0; j < 4; ++j) {
            const int ob = (w * 4 + j) * 512;              // wave-uniform LDS base
            const int c  = (ob >> 6) + (lane >> 3);        // local col 0..127
            const int kl = (lane & 7) << 3;
            const unsigned short* gp = w2t + (size_t)(t * NB + c) * HID + kc * 64 + kl;
            unsigned short* lp = &u.g.w2[buf][ob];
            __builtin_amdgcn_global_load_lds(
                (const __attribute__((address_space(1))) unsigned int*)gp,
                (__attribute__((address_space(3))) unsigned int*)lp, 16, 0, 0);
        }
    };

    float jf[2][4] = {{1.f,1.f,1.f,1.f},{1.f,1.f,1.f,1.f}};

    stage(0);
    #pragma unroll 1
    for (int t = 0; t < 8; ++t) {
        f32x4 acc[2][4];
        #pragma unroll
        for (int rt = 0; rt < 2; ++rt)
            #pragma unroll
            for (int ct = 0; ct < 4; ++ct) acc[rt][ct] = (f32x4){0.f, 0.f, 0.f, 0.f};

        #pragma unroll
        for (int kc = 0; kc < 4; ++kc) {          // STATIC unroll -> static afr idx
            __syncthreads();                       // chunk staged; prev buf readers done
            const int n = t * 4 + kc;
            if (n < 31) stage(n + 1);
            const unsigned short* wsb = u.g.w2[kc & 1];
            #pragma unroll
            for (int ks = 0; ks < 2; ++ks) {
                const int kf = kc * 2 + ks;        // compile-time
                const int klog = ks * 32 + quad * 8;
                #pragma unroll
                for (int ct = 0; ct < 4; ++ct) {
                    const int c = cw * 64 + ct * 16 + l15;
                    const bf16x8 bf = *(const bf16x8*)&wsb[c * 64 + (klog ^ ksw)];
                    acc[0][ct] = __builtin_amdgcn_mfma_f32_16x16x32_bf16(afr[0][kf], bf, acc[0][ct], 0, 0, 0);
                    acc[1][ct] = __builtin_amdgcn_mfma_f32_16x16x32_bf16(afr[1][kf], bf, acc[1][ct], 0, 0, 0);
                }
            }
        }

        // ---- local epilogue: 64-col partials (additive-merge form)
        float bb[4];
        #pragma unroll
        for (int ct = 0; ct < 4; ++ct)
            bb[ct] = b2[t * NB + cw * 64 + ct * 16 + l15] * LOG2E;

        float alpha_s[2][4];
        #pragma unroll
        for (int rt = 0; rt < 2; ++rt)
            #pragma unroll
            for (int i = 0; i < 4; ++i) {
                const int row = rw * 32 + rt * 16 + quad * 4 + i;
                const float alpha = xs[row * XC + 8 + t] * 128.f;   // broadcast
                alpha_s[rt][i] = alpha;
                const float fb = floorf(alpha);
                const int bin = min(max((int)fb, 0), 127);
                float e[4];
                #pragma unroll
                for (int ct = 0; ct < 4; ++ct) e[ct] = EXP2F(acc[rt][ct][i] + bb[ct]);
                const float P1 = e[0], P2 = P1 + e[1], P3 = P2 + e[2], P4 = P3 + e[3];
                const int bl = bin - cw * 64;              // local bin (<0 or >=64 ok)
                int thr = (bl - l15 + 15) >> 4;            // local cols < bl
                thr = min(max(thr, 0), 4);                 // clamp -> additive merge
                const float sA = (thr & 1) ? P1 : 0.f;
                const float sB = (thr & 1) ? P3 : P2;
                float num = (thr & 2) ? sB : sA;
                num = (thr >= 4) ? P4 : num;
                const int cbl = bl >> 4;
                const float t1 = (cbl & 1) ? e[1] : e[0];
                const float t2 = (cbl & 1) ? e[3] : e[2];
                const float es = (cbl & 2) ? t2 : t1;
                float eb = (((unsigned)bl < 64u) && ((bin & 15) == l15)) ? es : 0.f;
                float tot = P4;
                tot = red16(tot); num = red16(num); eb = red16(eb);
                if (l15 == 0) {
                    u.g.mrg[cw][row][0] = tot;
                    u.g.mrg[cw][row][1] = num;
                    u.g.mrg[cw][row][2] = eb;
                }
            }
        __syncthreads();                                   // publish partial triples

        // ---- symmetric combine (all waves; additive): rows owned by rw
        #pragma unroll
        for (int rt = 0; rt < 2; ++rt)
            #pragma unroll
            for (int i = 0; i < 4; ++i) {
                const int row = rw * 32 + rt * 16 + quad * 4 + i;
                const float T   = u.g.mrg[0][row][0] + u.g.mrg[1][row][0];
                const float nm  = u.g.mrg[0][row][1] + u.g.mrg[1][row][1];
                const float ebv = u.g.mrg[0][row][2] + u.g.mrg[1][row][2];
                const float alpha = alpha_s[rt][i];
                const float fr = alpha - floorf(alpha);
                const float inv = RCPF(T);
                jf[rt][i] *= 128.f * ebv * inv;
                if (cw == 0 && l15 == 0)
                    xs[row * XC + 8 + t] = fmaf(ebv, fr, nm) * inv;
            }
        // next t's kc=0 __syncthreads orders these mrg reads before rewrite
    }

    // jacobian into xs, then one fully-coalesced block copy-out
    if (cw == 0 && l15 == 0) {
        #pragma unroll
        for (int rt = 0; rt < 2; ++rt)
            #pragma unroll
            for (int i = 0; i < 4; ++i) {
                const int row = rw * 32 + rt * 16 + quad * 4 + i;
                xs[row * XC + 16] *= jf[rt][i];
            }
    }
    __syncthreads();
    for (int i = tid; i < ROWSB * XC; i += 256) out[r0 * XC + i] = xs[i];
}

extern "C" void kernel_launch(void* const* d_in, const int* in_sizes, int n_in,
                              void* d_out, int out_size, void* d_ws, size_t ws_size,
                              hipStream_t stream) {
    (void)in_sizes; (void)n_in; (void)ws_size; (void)out_size;
    prep_w2<<<128, 256, 0, stream>>>((const float*)d_in[3], (unsigned short*)d_ws);
    gplc6<<<NROWS / ROWSB, 256, 0, stream>>>(
        (const float*)d_in[0], (const float*)d_in[1], (const float*)d_in[2],
        (const unsigned short*)d_ws, (const float*)d_in[4], (float*)d_out);
}

// Round 10
// 167.006 us; speedup vs baseline: 1.3833x; 1.2213x over previous
//
#include <hip/hip_runtime.h>
#include <math.h>

#define NROWS 131072
#define XC    17      // FLOW_SIZE+1
#define ROWSB 128     // rows per block (R23: back to fat blocks, rt=2)
#define HID   256
#define NB    128
#define NCOL  1024
#define LOG2E 1.44269504088896340736f

typedef __attribute__((ext_vector_type(8))) short bf16x8;
typedef __attribute__((ext_vector_type(4))) float f32x4;

#if __has_builtin(__builtin_amdgcn_exp2f)
#define EXP2F(v) __builtin_amdgcn_exp2f(v)
#else
#define EXP2F(v) exp2f(v)
#endif
#if __has_builtin(__builtin_amdgcn_rcpf)
#define RCPF(v) __builtin_amdgcn_rcpf(v)
#else
#define RCPF(v) (1.f / (v))
#endif

__device__ __forceinline__ unsigned short f2bf(float f) {
    unsigned int u = __float_as_uint(f);
    return (unsigned short)((u + 0x7FFFu + ((u >> 16) & 1u)) >> 16);  // RNE
}

// 16-lane reduction on the VALU via DPP (validated; no LDS-pipe traffic).
__device__ __forceinline__ float red16(float v) {
    int x;
    x = __builtin_amdgcn_update_dpp(0, __float_as_int(v), 0xB1, 0xF, 0xF, true);
    v += __int_as_float(x);
    x = __builtin_amdgcn_update_dpp(0, __float_as_int(v), 0x4E, 0xF, 0xF, true);
    v += __int_as_float(x);
    x = __builtin_amdgcn_update_dpp(0, __float_as_int(v), 0x141, 0xF, 0xF, true);
    v += __int_as_float(x);
    x = __builtin_amdgcn_update_dpp(0, __float_as_int(v), 0x140, 0xF, 0xF, true);
    v += __int_as_float(x);
    return v;
}

// R23 prep: FRAGMENT-LINEAR W2 pack. Fragment F=(t,kc,ks,ct) holds the exact
// B-operand of one 16x16x32 MFMA: 1 KB contiguous, lane-order (lane*16B),
// element = W2[kc*64+ks*32+quad*8+j][t*128+ct*16+l15]*LOG2E as bf16.
// A fragment load in the main kernel is then ONE perfectly-coalesced
// global_load_dwordx4 per lane (1 KB/instr) served from L2 (512 KB total).
__global__ void prep_w2f(const float* __restrict__ W2, unsigned short* __restrict__ w2f) {
    const int tid  = threadIdx.x;
    const int F    = blockIdx.x * 4 + (tid >> 6);   // 128 blocks x 4 frags
    const int lane = tid & 63;
    const int quad = lane >> 4, l15 = lane & 15;
    const int ct = F & 7, ks = (F >> 3) & 1, kc = (F >> 4) & 3, t = F >> 6;
    const int k0  = kc * 64 + ks * 32 + quad * 8;
    const int col = t * NB + ct * 16 + l15;
    unsigned int p[4];
    #pragma unroll
    for (int jj = 0; jj < 4; ++jj) {
        const unsigned short lo = f2bf(W2[(size_t)(k0 + 2 * jj)     * NCOL + col] * LOG2E);
        const unsigned short hi = f2bf(W2[(size_t)(k0 + 2 * jj + 1) * NCOL + col] * LOG2E);
        p[jj] = (unsigned int)lo | ((unsigned int)hi << 16);
    }
    uint4 q; q.x = p[0]; q.y = p[1]; q.z = p[2]; q.w = p[3];
    *(uint4*)&w2f[(size_t)F * 512 + lane * 8] = q;
}

// R23: BARRIER-FREE t-loop. Every clean variant (R16-R22) pinned 117-159us
// with no pipe saturated; the shared invariant was the 32-64 barrier
// rendezvous per block (~45 serial segments x ~2.3K cyc each vs ~300 cyc of
// work). W2 bf16 = 512 KB = L2-resident per XCD, so B needs NO LDS at all:
// waves stream fragment-linear B direct global->VGPR with a static 2-buffer
// slice pipeline (8 frags in flight while 8 compute). Zero __syncthreads in
// the t-loop; waves drift and self-overlap. rt=2 amortizes each fragment
// over 2 MFMAs. LDS (xs+hb, 74240 B) is prologue-only. 2 waves/SIMD by regs;
// latency hidden by ILP + drift, not TLP.
__global__ __launch_bounds__(256, 2)
void gplc6(const float* __restrict__ x,
           const float* __restrict__ W1,
           const float* __restrict__ b1,
           const unsigned short* __restrict__ w2f,
           const float* __restrict__ b2,
           float* __restrict__ out)
{
    __shared__ float xs[ROWSB * XC];                       // 8704 B
    __shared__ __align__(16) unsigned short hb[ROWSB * HID]; // 64 KB (prologue only)

    const int tid  = threadIdx.x;
    const int lane = tid & 63;
    const int w    = tid >> 6;        // wave 0..3 -> rows w*32..w*32+31
    const int quad = lane >> 4;
    const int l15  = lane & 15;
    const int wr   = w * 32;
    const size_t r0 = (size_t)blockIdx.x * ROWSB;

    for (int i = tid; i < ROWSB * XC; i += 256) xs[i] = x[r0 * XC + i];
    const int cp = tid & 127, hlf = tid >> 7;
    float w1r[16];
    #pragma unroll
    for (int i = 0; i < 8; ++i) {
        const float2 t2 = *(const float2*)&W1[i * HID + 2 * cp];
        w1r[2 * i] = t2.x; w1r[2 * i + 1] = t2.y;
    }
    const float2 b1v = *(const float2*)&b1[2 * cp];
    __syncthreads();

    // ---- phase 1 (R0-validated): h = relu(xA@W1+b1) -> bf16 LDS,
    // granule-XOR row swizzle; 128 col-pair threads x 64 rows each half.
    for (int r = 0; r < 64; ++r) {
        const int row = hlf * 64 + r;
        float a0 = b1v.x, a1 = b1v.y;
        #pragma unroll
        for (int i = 0; i < 8; ++i) {
            const float xv = xs[row * XC + i];
            a0 = fmaf(xv, w1r[2 * i], a0);
            a1 = fmaf(xv, w1r[2 * i + 1], a1);
        }
        a0 = fmaxf(a0, 0.f); a1 = fmaxf(a1, 0.f);
        const int eidx = row * HID + (((cp >> 2) ^ (row & 15)) << 3) + ((cp & 3) << 1);
        *(unsigned int*)&hb[eidx] = (unsigned int)f2bf(a0) | ((unsigned int)f2bf(a1) << 16);
    }
    __syncthreads();

    // ---- A-fragment register cache (R0-validated): 32 rows x 256 K / wave.
    bf16x8 afr[2][8];
    #pragma unroll
    for (int rt = 0; rt < 2; ++rt)
        #pragma unroll
        for (int kf = 0; kf < 8; ++kf) {
            const int row = wr + rt * 16 + l15;    // row&15 == l15
            afr[rt][kf] = *(const bf16x8*)&hb[row * HID + (((kf * 4 + quad) ^ l15) << 3)];
        }
    // hb dead from here; NO further cross-wave LDS use until copy-out.

    // slice g = t*8 + s (s = kc*2+ks = kf): 8 fragments, 8 KB, one
    // global_load_dwordx4 per lane per fragment, fully coalesced.
    const int loff = lane * 8;
    auto loadslice = [&](bf16x8* d, int g) {
        const unsigned short* fp = w2f + (size_t)g * 4096 + loff;
        #pragma unroll
        for (int ct = 0; ct < 8; ++ct)
            d[ct] = *(const bf16x8*)&fp[ct * 512];
    };

    float jf[2][4] = {{1.f,1.f,1.f,1.f},{1.f,1.f,1.f,1.f}};
    bf16x8 bA[8], bB[8];

#define SLICE_MFMA(CUR, KF)                                                     \
    {                                                                           \
        __builtin_amdgcn_s_setprio(1);                                          \
        _Pragma("unroll")                                                       \
        for (int ct = 0; ct < 8; ++ct) {                                        \
            acc[0][ct] = __builtin_amdgcn_mfma_f32_16x16x32_bf16(               \
                afr[0][KF], CUR[ct], acc[0][ct], 0, 0, 0);                      \
            acc[1][ct] = __builtin_amdgcn_mfma_f32_16x16x32_bf16(               \
                afr[1][KF], CUR[ct], acc[1][ct], 0, 0, 0);                      \
        }                                                                       \
        __builtin_amdgcn_s_setprio(0);                                          \
    }

    loadslice(bA, 0);
    #pragma unroll 1
    for (int t = 0; t < 8; ++t) {
        f32x4 acc[2][8];
        #pragma unroll
        for (int rt = 0; rt < 2; ++rt)
            #pragma unroll
            for (int ct = 0; ct < 8; ++ct) acc[rt][ct] = (f32x4){0.f, 0.f, 0.f, 0.f};

        float bb[8];
        #pragma unroll
        for (int ct = 0; ct < 8; ++ct) bb[ct] = b2[t * NB + ct * 16 + l15] * LOG2E;

        const int g0 = t * 8;
        #pragma unroll
        for (int sp = 0; sp < 4; ++sp) {
            // even slice: consume bA, prefetch g+1 into bB
            {
                const int g = g0 + 2 * sp;
                if (g < 63) loadslice(bB, g + 1);
                SLICE_MFMA(bA, 2 * sp)
            }
            // odd slice: consume bB, prefetch g+2 into bA
            {
                const int g = g0 + 2 * sp + 1;
                if (g < 63) loadslice(bA, g + 1);
                SLICE_MFMA(bB, 2 * sp + 1)
            }
        }

        // ---- fused epilogue (R0-validated shape); rows are wave-exclusive,
        // xs slot t is read+written only by the owning wave -> no barrier.
        #pragma unroll
        for (int rt = 0; rt < 2; ++rt)
            #pragma unroll
            for (int i = 0; i < 4; ++i) {
                const int row = wr + rt * 16 + quad * 4 + i;
                const float alpha = xs[row * XC + 8 + t] * 128.f;   // broadcast
                const float fb = floorf(alpha);
                const int bin = min(max((int)fb, 0), 127);
                const float fr = alpha - fb;
                float e[8];
                #pragma unroll
                for (int ct = 0; ct < 8; ++ct) e[ct] = EXP2F(acc[rt][ct][i] + bb[ct]);
                const float P1 = e[0],      P2 = P1 + e[1], P3 = P2 + e[2], P4 = P3 + e[3];
                const float P5 = P4 + e[4], P6 = P5 + e[5], P7 = P6 + e[6], P8 = P7 + e[7];
                int thr = (bin - l15 + 15) >> 4;           // ceil((bin-l15)/16)
                thr = min(max(thr, 0), 8);
                const float sA = (thr & 1) ? P1 : 0.f;
                const float sB = (thr & 1) ? P3 : P2;
                const float sC = (thr & 1) ? P5 : P4;
                const float sD = (thr & 1) ? P7 : P6;
                const float sE = (thr & 2) ? sB : sA;
                const float sF = (thr & 2) ? sD : sC;
                float num = (thr & 4) ? sF : sE;
                num = (thr >= 8) ? P8 : num;
                const int cb = bin >> 4;
                const float t1 = (cb & 1) ? e[1] : e[0];
                const float t2 = (cb & 1) ? e[3] : e[2];
                const float t3 = (cb & 1) ? e[5] : e[4];
                const float t4 = (cb & 1) ? e[7] : e[6];
                const float u1 = (cb & 2) ? t2 : t1;
                const float u2 = (cb & 2) ? t4 : t3;
                const float es = (cb & 4) ? u2 : u1;
                float eb  = ((bin & 15) == l15) ? es : 0.f;
                float tot = P8;
                tot = red16(tot); num = red16(num); eb = red16(eb);
                const float inv = RCPF(tot);
                jf[rt][i] *= 128.f * eb * inv;
                if (l15 == 0) xs[row * XC + 8 + t] = fmaf(eb, fr, num) * inv;
            }
    }
#undef SLICE_MFMA

    // jacobian into xs, then one fully-coalesced block copy-out
    if (l15 == 0) {
        #pragma unroll
        for (int rt = 0; rt < 2; ++rt)
            #pragma unroll
            for (int i = 0; i < 4; ++i) {
                const int row = wr + rt * 16 + quad * 4 + i;
                xs[row * XC + 16] *= jf[rt][i];
            }
    }
    __syncthreads();     // the ONLY post-prologue barrier
    for (int i = tid; i < ROWSB * XC; i += 256) out[r0 * XC + i] = xs[i];
}

extern "C" void kernel_launch(void* const* d_in, const int* in_sizes, int n_in,
                              void* d_out, int out_size, void* d_ws, size_t ws_size,
                              hipStream_t stream) {
    (void)in_sizes; (void)n_in; (void)ws_size; (void)out_size;
    prep_w2f<<<128, 256, 0, stream>>>((const float*)d_in[3], (unsigned short*)d_ws);
    gplc6<<<NROWS / ROWSB, 256, 0, stream>>>(
        (const float*)d_in[0], (const float*)d_in[1], (const float*)d_in[2],
        (const unsigned short*)d_ws, (const float*)d_in[4], (float*)d_out);
}